// Round 2
// baseline (584.208 us; speedup 1.0000x reference)
//
#include <hip/hip_runtime.h>
#include <hip/hip_bf16.h>
#include <math.h>

#define B 16
#define N 512
#define L 512
#define DIM 10
#define DM 128
#define H 8
#define DK 16
#define DFF 512
#define LG 3
#define LO 3
#define NEGV -9.0e15f
#define RF 16     // rows per block (ffn/qkv/oproj)
#define AQR 64    // q-rows per attn block

__device__ __forceinline__ float wave_reduce_sum(float v) {
    #pragma unroll
    for (int o = 32; o > 0; o >>= 1) v += __shfl_down(v, o, 64);
    return v;
}

// ---------------- GNN ----------------

__global__ void k_embed_fp(const int* __restrict__ fing, const float* __restrict__ emb_fp,
                           float* __restrict__ xs) {
    int idx = blockIdx.x * blockDim.x + threadIdx.x;
    if (idx >= B * N * DIM) return;
    int d = idx % DIM;
    int bn = idx / DIM;
    xs[idx] = emb_fp[fing[bn] * DIM + d];
}

__global__ void k_gnn_h(const float* __restrict__ xs, const float* __restrict__ fp_mask,
                        const float* __restrict__ Wg, const float* __restrict__ bg,
                        const float* __restrict__ aatt,
                        float* __restrict__ h, float* __restrict__ s1, float* __restrict__ s2) {
    int bn = blockIdx.x * blockDim.x + threadIdx.x;
    if (bn >= B * N) return;
    float x[DIM];
    #pragma unroll
    for (int d = 0; d < DIM; d++) x[d] = xs[bn * DIM + d];
    float m = fp_mask[bn];
    float a1 = 0.f, a2 = 0.f;
    #pragma unroll
    for (int j = 0; j < DIM; j++) {
        float acc = bg[j];
        #pragma unroll
        for (int d = 0; d < DIM; d++) acc += x[d] * Wg[d * DIM + j];
        acc = fmaxf(acc, 0.f) * m;
        h[bn * DIM + j] = acc;
        a1 += acc * aatt[j];
        a2 += acc * aatt[DIM + j];
    }
    s1[bn] = a1;
    s2[bn] = a2;
}

// 16 lane-groups of 16 lanes; each group owns one row. grid = B*(N/16), 256 thr.
__global__ void k_gnn_att(const float* __restrict__ h, const float* __restrict__ s1,
                          const float* __restrict__ s2, const int* __restrict__ adj,
                          float* __restrict__ xs) {
    int b  = blockIdx.x / (N / 16);
    int rg = blockIdx.x % (N / 16);
    int t = threadIdx.x;
    int g  = t >> 4;   // group 0..15
    int ll = t & 15;   // lane in group
    int i = rg * 16 + g;

    __shared__ float h_s[N * DIM];   // 20KB
    __shared__ float s2_s[N];        // 2KB

    const float* hb = h + (long)b * N * DIM;
    for (int idx = t; idx < N * DIM; idx += 256) h_s[idx] = hb[idx];
    for (int j = t; j < N; j += 256) s2_s[j] = s2[b * N + j];
    __syncthreads();

    float s1v = s1[b * N + i];
    const int* adjrow = adj + ((long)b * N + i) * N;

    float e[32];
    #pragma unroll
    for (int c = 0; c < 32; c++) {
        int j = c * 16 + ll;
        float xsc = s1v + s2_s[j];
        xsc = xsc > 0.f ? xsc : 0.01f * xsc;
        e[c] = (adjrow[j] > 0) ? xsc : NEGV;
    }
    float m = e[0];
    #pragma unroll
    for (int c = 1; c < 32; c++) m = fmaxf(m, e[c]);
    #pragma unroll
    for (int off = 1; off < 16; off <<= 1) m = fmaxf(m, __shfl_xor(m, off, 64));

    float sum = 0.f;
    float a[DIM];
    #pragma unroll
    for (int d = 0; d < DIM; d++) a[d] = 0.f;
    #pragma unroll
    for (int c = 0; c < 32; c++) {
        float p = expf(e[c] - m);
        sum += p;
        int j = c * 16 + ll;
        #pragma unroll
        for (int d = 0; d < DIM; d++) a[d] += p * h_s[j * DIM + d];
    }
    #pragma unroll
    for (int off = 1; off < 16; off <<= 1) {
        sum += __shfl_xor(sum, off, 64);
        #pragma unroll
        for (int d = 0; d < DIM; d++) a[d] += __shfl_xor(a[d], off, 64);
    }
    if (ll < DIM) {
        // static-index select (avoid runtime-indexed register array -> scratch)
        float av = a[0];
        if (ll == 1) av = a[1]; else if (ll == 2) av = a[2]; else if (ll == 3) av = a[3];
        else if (ll == 4) av = a[4]; else if (ll == 5) av = a[5]; else if (ll == 6) av = a[6];
        else if (ll == 7) av = a[7]; else if (ll == 8) av = a[8]; else if (ll == 9) av = a[9];
        xs[((long)b * N + i) * DIM + ll] += av / sum;
    }
}

__global__ void k_compound(const float* __restrict__ xs, const float* __restrict__ fp_mask,
                           const float* __restrict__ Watt, const float* __restrict__ batt,
                           float* __restrict__ compound, float* __restrict__ hc) {
    int b = blockIdx.x;
    int t = threadIdx.x;  // 256
    int wid = t >> 6, lane = t & 63;
    float lacc[DIM];
    #pragma unroll
    for (int d = 0; d < DIM; d++) lacc[d] = 0.f;
    for (int n = t; n < N; n += 256) {
        float m = fp_mask[b * N + n];
        #pragma unroll
        for (int d = 0; d < DIM; d++) lacc[d] += xs[((long)b * N + n) * DIM + d] * m;
    }
    __shared__ float red[4][DIM];
    __shared__ float comp_s[DIM];
    #pragma unroll
    for (int d = 0; d < DIM; d++) lacc[d] = wave_reduce_sum(lacc[d]);
    if (lane == 0) {
        #pragma unroll
        for (int d = 0; d < DIM; d++) red[wid][d] = lacc[d];
    }
    __syncthreads();
    if (t < DIM) {
        float c = (red[0][t] + red[1][t] + red[2][t] + red[3][t]) / (float)N;
        compound[b * DIM + t] = c;
        comp_s[t] = c;
    }
    __syncthreads();
    if (t < DIM) {
        float acc = batt[t];
        #pragma unroll
        for (int e = 0; e < DIM; e++) acc += comp_s[e] * Watt[e * DIM + t];
        hc[b * DIM + t] = fmaxf(acc, 0.f);
    }
}

// ---------------- Transformer ----------------

__global__ void k_pe(float* __restrict__ pe) {
    int idx = blockIdx.x * blockDim.x + threadIdx.x;
    if (idx >= L * DM) return;
    int d = idx % DM, l = idx / DM;
    int k = d >> 1;
    double div = exp((double)(2 * k) * (-log(10000.0) / (double)DM));
    double ang = (double)l * div;
    pe[idx] = (d & 1) ? (float)cos(ang) : (float)sin(ang);
}

__global__ void k_embed_word(const int* __restrict__ words, const float* __restrict__ emb,
                             const float* __restrict__ pe, float* __restrict__ x) {
    long idx = (long)blockIdx.x * blockDim.x + threadIdx.x;
    if (idx >= (long)B * L * DM) return;
    int d = idx % DM;
    long bl = idx / DM;
    int l = (int)(bl % L);
    x[idx] = emb[(long)words[bl] * DM + d] * sqrtf(128.0f) + pe[l * DM + d];
}

__global__ void k_layernorm(const float* __restrict__ x, const float* __restrict__ g,
                            const float* __restrict__ bb, float* __restrict__ out) {
    int row = blockIdx.x;
    int t = threadIdx.x;  // 128
    int wid = t >> 6, lane = t & 63;
    float v = x[(long)row * DM + t];
    float s = wave_reduce_sum(v);
    __shared__ float r2[2], r3[2];
    if (lane == 0) r2[wid] = s;
    __syncthreads();
    float mean = (r2[0] + r2[1]) / (float)DM;
    float dv = v - mean;
    float q = wave_reduce_sum(dv * dv);
    if (lane == 0) r3[wid] = q;
    __syncthreads();
    float sd = sqrtf((r3[0] + r3[1]) / (float)(DM - 1)) + 1e-6f;
    out[(long)row * DM + t] = g[t] * dv / sd + bb[t];
}

// 16 rows per block, 384 threads: thread = (proj, out-col)
__global__ void k_qkv(const float* __restrict__ xn,
                      const float* __restrict__ Wq, const float* __restrict__ bq,
                      const float* __restrict__ Wk, const float* __restrict__ bk,
                      const float* __restrict__ Wv, const float* __restrict__ bv,
                      float* __restrict__ q, float* __restrict__ k, float* __restrict__ v) {
    long row0 = (long)blockIdx.x * RF;
    int t = threadIdx.x;  // 384
    __shared__ float xs_s[RF * DM];
    for (int i = t; i < RF * DM; i += 384) xs_s[i] = xn[row0 * DM + i];
    __syncthreads();
    int proj = t / DM;
    int j = t % DM;
    const float* W    = proj == 0 ? Wq : (proj == 1 ? Wk : Wv);
    const float* bias = proj == 0 ? bq : (proj == 1 ? bk : bv);
    float* out        = proj == 0 ? q  : (proj == 1 ? k  : v);
    float acc[RF];
    #pragma unroll
    for (int r = 0; r < RF; r++) acc[r] = bias[j];
    for (int d = 0; d < DM; d++) {
        float w = W[d * DM + j];
        #pragma unroll
        for (int r = 0; r < RF; r++) acc[r] += xs_s[r * DM + d] * w;
    }
    #pragma unroll
    for (int r = 0; r < RF; r++) {
        long row = row0 + r;
        int b = (int)(row / L), l = (int)(row % L);
        out[(((long)b * H + j / DK) * L + l) * DK + (j % DK)] = acc[r];
    }
}

// 4-segment online softmax attention. grid = B*H*(L/AQR), 256 threads.
// thread: seg = t&3 (128 keys each), r = t>>2 (q-row in block).
__global__ void k_attn(const float* __restrict__ q, const float* __restrict__ k,
                       const float* __restrict__ v, const float* __restrict__ wmask,
                       float* __restrict__ attnout) {
    int blk = blockIdx.x;
    int qc = blk % (L / AQR);
    int bh = blk / (L / AQR);
    int b = bh / H, hh = bh % H;
    int t = threadIdx.x;   // 256
    int seg = t & 3;
    int r = t >> 2;
    int l = qc * AQR + r;

    __shared__ float4 k_s[L * 4];   // 32KB
    __shared__ float wm_s[L];       // 2KB
    const float4* kb4 = (const float4*)(k + (long)bh * L * DK);
    for (int i = t; i < L * 4; i += 256) k_s[i] = kb4[i];
    for (int j = t; j < L; j += 256) wm_s[j] = wmask[b * L + j];
    __syncthreads();

    const float4* qrow = (const float4*)(q + ((long)bh * L + l) * DK);
    float4 qr0 = qrow[0], qr1 = qrow[1], qr2 = qrow[2], qr3 = qrow[3];
    qr0.x *= 0.25f; qr0.y *= 0.25f; qr0.z *= 0.25f; qr0.w *= 0.25f;
    qr1.x *= 0.25f; qr1.y *= 0.25f; qr1.z *= 0.25f; qr1.w *= 0.25f;
    qr2.x *= 0.25f; qr2.y *= 0.25f; qr2.z *= 0.25f; qr2.w *= 0.25f;
    qr3.x *= 0.25f; qr3.y *= 0.25f; qr3.z *= 0.25f; qr3.w *= 0.25f;

    const float4* vb4 = (const float4*)(v + (long)bh * L * DK);

    float m = -1e30f, ssum = 0.f;
    float4 acc0 = make_float4(0,0,0,0), acc1 = make_float4(0,0,0,0);
    float4 acc2 = make_float4(0,0,0,0), acc3 = make_float4(0,0,0,0);

    int jbase = seg * (L / 4);
    for (int c = 0; c < (L / 4) / 8; c++) {
        int j0 = jbase + c * 8;
        float s8[8];
        #pragma unroll
        for (int jj = 0; jj < 8; jj++) {
            int j = j0 + jj;
            float4 k0 = k_s[j * 4 + 0], k1 = k_s[j * 4 + 1];
            float4 k2 = k_s[j * 4 + 2], k3 = k_s[j * 4 + 3];
            float s = qr0.x * k0.x + qr0.y * k0.y + qr0.z * k0.z + qr0.w * k0.w
                    + qr1.x * k1.x + qr1.y * k1.y + qr1.z * k1.z + qr1.w * k1.w
                    + qr2.x * k2.x + qr2.y * k2.y + qr2.z * k2.z + qr2.w * k2.w
                    + qr3.x * k3.x + qr3.y * k3.y + qr3.z * k3.z + qr3.w * k3.w;
            s8[jj] = (wm_s[j] > 0.f) ? s : -1e9f;
        }
        float cm = fmaxf(fmaxf(fmaxf(s8[0], s8[1]), fmaxf(s8[2], s8[3])),
                         fmaxf(fmaxf(s8[4], s8[5]), fmaxf(s8[6], s8[7])));
        float mn = fmaxf(m, cm);
        float scale = expf(m - mn);
        ssum *= scale;
        acc0.x *= scale; acc0.y *= scale; acc0.z *= scale; acc0.w *= scale;
        acc1.x *= scale; acc1.y *= scale; acc1.z *= scale; acc1.w *= scale;
        acc2.x *= scale; acc2.y *= scale; acc2.z *= scale; acc2.w *= scale;
        acc3.x *= scale; acc3.y *= scale; acc3.z *= scale; acc3.w *= scale;
        #pragma unroll
        for (int jj = 0; jj < 8; jj++) {
            int j = j0 + jj;
            float p = expf(s8[jj] - mn);
            ssum += p;
            float4 v0 = vb4[j * 4 + 0], v1 = vb4[j * 4 + 1];
            float4 v2 = vb4[j * 4 + 2], v3 = vb4[j * 4 + 3];
            acc0.x += p * v0.x; acc0.y += p * v0.y; acc0.z += p * v0.z; acc0.w += p * v0.w;
            acc1.x += p * v1.x; acc1.y += p * v1.y; acc1.z += p * v1.z; acc1.w += p * v1.w;
            acc2.x += p * v2.x; acc2.y += p * v2.y; acc2.z += p * v2.z; acc2.w += p * v2.w;
            acc3.x += p * v3.x; acc3.y += p * v3.y; acc3.z += p * v3.z; acc3.w += p * v3.w;
        }
        m = mn;
    }

    // merge 4 segment states across lanes (seg = lane bits 0..1)
    #pragma unroll
    for (int off = 1; off <= 2; off <<= 1) {
        float m2  = __shfl_xor(m, off, 64);
        float ss2 = __shfl_xor(ssum, off, 64);
        float mn = fmaxf(m, m2);
        float ea = expf(m - mn), eb = expf(m2 - mn);
        ssum = ssum * ea + ss2 * eb;
        #define MRG(f) { float o_ = __shfl_xor(f, off, 64); f = f * ea + o_ * eb; }
        MRG(acc0.x) MRG(acc0.y) MRG(acc0.z) MRG(acc0.w)
        MRG(acc1.x) MRG(acc1.y) MRG(acc1.z) MRG(acc1.w)
        MRG(acc2.x) MRG(acc2.y) MRG(acc2.z) MRG(acc2.w)
        MRG(acc3.x) MRG(acc3.y) MRG(acc3.z) MRG(acc3.w)
        #undef MRG
        m = mn;
    }

    float inv = 1.f / ssum;
    float4 w4;
    w4.x = seg == 0 ? acc0.x : seg == 1 ? acc1.x : seg == 2 ? acc2.x : acc3.x;
    w4.y = seg == 0 ? acc0.y : seg == 1 ? acc1.y : seg == 2 ? acc2.y : acc3.y;
    w4.z = seg == 0 ? acc0.z : seg == 1 ? acc1.z : seg == 2 ? acc2.z : acc3.z;
    w4.w = seg == 0 ? acc0.w : seg == 1 ? acc1.w : seg == 2 ? acc2.w : acc3.w;
    float4* outp = (float4*)(attnout + ((long)b * L + l) * DM + hh * DK);
    outp[seg] = make_float4(w4.x * inv, w4.y * inv, w4.z * inv, w4.w * inv);
}

// x += attnout @ Wo + bo ; 16 rows/block, 128 threads
__global__ void k_oproj(const float* __restrict__ attnout, const float* __restrict__ Wo,
                        const float* __restrict__ bo, float* __restrict__ x) {
    long row0 = (long)blockIdx.x * RF;
    int t = threadIdx.x;  // 128
    __shared__ float a_s[RF * DM];
    for (int i = t; i < RF * DM; i += 128) a_s[i] = attnout[row0 * DM + i];
    __syncthreads();
    float acc[RF];
    #pragma unroll
    for (int r = 0; r < RF; r++) acc[r] = bo[t];
    for (int d = 0; d < DM; d++) {
        float w = Wo[d * DM + t];
        #pragma unroll
        for (int r = 0; r < RF; r++) acc[r] += a_s[r * DM + d] * w;
    }
    #pragma unroll
    for (int r = 0; r < RF; r++) x[(row0 + r) * DM + t] += acc[r];
}

// fused FFN: x += relu(xn@W1+b1)@W2+b2 ; 16 rows/block, 512 threads
__global__ void k_ffn(const float* __restrict__ xn, const float* __restrict__ W1,
                      const float* __restrict__ b1, const float* __restrict__ W2,
                      const float* __restrict__ b2, float* __restrict__ x) {
    long row0 = (long)blockIdx.x * RF;
    int t = threadIdx.x;  // 512
    __shared__ float xs_s[RF * DM];    // 8KB
    __shared__ float h_s[RF * DFF];    // 32KB
    for (int i = t; i < RF * DM; i += 512) xs_s[i] = xn[row0 * DM + i];
    __syncthreads();
    {
        float acc[RF];
        #pragma unroll
        for (int r = 0; r < RF; r++) acc[r] = b1[t];
        for (int d = 0; d < DM; d++) {
            float w = W1[d * DFF + t];
            #pragma unroll
            for (int r = 0; r < RF; r++) acc[r] += xs_s[r * DM + d] * w;
        }
        #pragma unroll
        for (int r = 0; r < RF; r++) h_s[r * DFF + t] = fmaxf(acc[r], 0.f);
    }
    __syncthreads();
    int col = t & 127, rq = t >> 7;   // rq uniform per wave
    float acc2[4];
    #pragma unroll
    for (int rr = 0; rr < 4; rr++) acc2[rr] = b2[col];
    for (int f = 0; f < DFF; f++) {
        float w = W2[f * DM + col];
        #pragma unroll
        for (int rr = 0; rr < 4; rr++) acc2[rr] += h_s[(rq * 4 + rr) * DFF + f] * w;
    }
    #pragma unroll
    for (int rr = 0; rr < 4; rr++) x[(row0 + rq * 4 + rr) * DM + col] += acc2[rr];
}

// lnf -> relu -> Wtout -> Watt/relu -> hp ; per row, 128 threads
__global__ void k_lnf_hp(const float* __restrict__ x, const float* __restrict__ g,
                         const float* __restrict__ bb, const float* __restrict__ Wtout,
                         const float* __restrict__ btout, const float* __restrict__ Watt,
                         const float* __restrict__ batt, float* __restrict__ hp) {
    int row = blockIdx.x;
    int t = threadIdx.x;  // 128
    int wid = t >> 6, lane = t & 63;
    float v = x[(long)row * DM + t];
    float s = wave_reduce_sum(v);
    __shared__ float r2[2], r3[2];
    if (lane == 0) r2[wid] = s;
    __syncthreads();
    float mean = (r2[0] + r2[1]) / (float)DM;
    float dv = v - mean;
    float qq = wave_reduce_sum(dv * dv);
    if (lane == 0) r3[wid] = qq;
    __syncthreads();
    float sd = sqrtf((r3[0] + r3[1]) / (float)(DM - 1)) + 1e-6f;
    float xnv = g[t] * dv / sd + bb[t];
    __shared__ float rrelu[DM];
    rrelu[t] = fmaxf(xnv, 0.f);
    __syncthreads();
    __shared__ float wv_s[DIM];
    if (t < DIM) {
        float acc = btout[t];
        for (int d = 0; d < DM; d++) acc += rrelu[d] * Wtout[d * DIM + t];
        wv_s[t] = acc;
    }
    __syncthreads();
    if (t < DIM) {
        float acc = batt[t];
        #pragma unroll
        for (int e = 0; e < DIM; e++) acc += wv_s[e] * Watt[e * DIM + t];
        hp[(long)row * DIM + t] = fmaxf(acc, 0.f);
    }
}

__global__ void k_final(const float* __restrict__ hp, const float* __restrict__ hc,
                        const float* __restrict__ compound, const float* __restrict__ Wout,
                        const float* __restrict__ bout, const float* __restrict__ Wint,
                        const float* __restrict__ bint, float* __restrict__ out) {
    int b = blockIdx.x;
    int t = threadIdx.x;  // 256
    int wid = t >> 6, lane = t & 63;
    __shared__ float hc_s[DIM];
    if (t < DIM) hc_s[t] = hc[b * DIM + t];
    __syncthreads();
    float lacc[DIM];
    #pragma unroll
    for (int e = 0; e < DIM; e++) lacc[e] = 0.f;
    for (int l = t; l < L; l += 256) {
        const float* hpl = hp + ((long)b * L + l) * DIM;
        float hv[DIM];
        float dot = 0.f;
        #pragma unroll
        for (int e = 0; e < DIM; e++) { hv[e] = hpl[e]; dot += hc_s[e] * hv[e]; }
        float w = tanhf(dot);
        #pragma unroll
        for (int e = 0; e < DIM; e++) lacc[e] += w * hv[e];
    }
    __shared__ float red[4][DIM];
    #pragma unroll
    for (int e = 0; e < DIM; e++) lacc[e] = wave_reduce_sum(lacc[e]);
    if (lane == 0) {
        #pragma unroll
        for (int e = 0; e < DIM; e++) red[wid][e] = lacc[e];
    }
    __syncthreads();
    if (t == 0) {
        float cat[2 * DIM], tmp[2 * DIM];
        for (int e = 0; e < DIM; e++) cat[e] = compound[b * DIM + e];
        for (int e = 0; e < DIM; e++)
            cat[DIM + e] = (red[0][e] + red[1][e] + red[2][e] + red[3][e]) / (float)L;
        for (int j = 0; j < LO; j++) {
            const float* W = Wout + j * 2 * DIM * 2 * DIM;
            const float* bj = bout + j * 2 * DIM;
            for (int o = 0; o < 2 * DIM; o++) {
                float acc = bj[o];
                for (int e = 0; e < 2 * DIM; e++) acc += cat[e] * W[e * 2 * DIM + o];
                tmp[o] = fmaxf(acc, 0.f);
            }
            for (int o = 0; o < 2 * DIM; o++) cat[o] = tmp[o];
        }
        float o0 = bint[0], o1 = bint[1];
        for (int e = 0; e < 2 * DIM; e++) {
            o0 += cat[e] * Wint[e * 2 + 0];
            o1 += cat[e] * Wint[e * 2 + 1];
        }
        out[b * 2 + 0] = o0;
        out[b * 2 + 1] = o1;
    }
}

extern "C" void kernel_launch(void* const* d_in, const int* in_sizes, int n_in,
                              void* d_out, int out_size, void* d_ws, size_t ws_size,
                              hipStream_t stream) {
    (void)in_sizes; (void)n_in; (void)out_size; (void)ws_size;
    const int*   fingerprints = (const int*)d_in[0];
    const float* fp_mask      = (const float*)d_in[1];
    const int*   adjacency    = (const int*)d_in[2];
    const int*   words        = (const int*)d_in[3];
    const float* words_mask   = (const float*)d_in[4];
    const float* emb_fp       = (const float*)d_in[5];
    const float* emb_word     = (const float*)d_in[6];
    const float* Wg   = (const float*)d_in[7];
    const float* bg   = (const float*)d_in[8];
    const float* attn_a = (const float*)d_in[9];
    const float* Wq = (const float*)d_in[10];
    const float* bq = (const float*)d_in[11];
    const float* Wk = (const float*)d_in[12];
    const float* bk = (const float*)d_in[13];
    const float* Wv = (const float*)d_in[14];
    const float* bv = (const float*)d_in[15];
    const float* Wo = (const float*)d_in[16];
    const float* bo = (const float*)d_in[17];
    const float* ln1_g = (const float*)d_in[18];
    const float* ln1_b = (const float*)d_in[19];
    const float* ln2_g = (const float*)d_in[20];
    const float* ln2_b = (const float*)d_in[21];
    const float* lnf_g = (const float*)d_in[22];
    const float* lnf_b = (const float*)d_in[23];
    const float* W1 = (const float*)d_in[24];
    const float* b1 = (const float*)d_in[25];
    const float* W2 = (const float*)d_in[26];
    const float* b2 = (const float*)d_in[27];
    const float* Wtout = (const float*)d_in[28];
    const float* btout = (const float*)d_in[29];
    const float* Watt  = (const float*)d_in[30];
    const float* batt  = (const float*)d_in[31];
    const float* Wout  = (const float*)d_in[32];
    const float* bout  = (const float*)d_in[33];
    const float* Wint  = (const float*)d_in[34];
    const float* bint  = (const float*)d_in[35];
    float* out = (float*)d_out;

    float* w = (float*)d_ws;
    float* xs = w;        w += B * N * DIM;
    float* h  = w;        w += B * N * DIM;
    float* s1 = w;        w += B * N;
    float* s2 = w;        w += B * N;
    float* compound = w;  w += B * DIM;
    float* hc = w;        w += B * DIM;
    float* pe = w;        w += L * DM;
    float* x  = w;        w += (long)B * L * DM;
    float* xn = w;        w += (long)B * L * DM;
    float* qb = w;        w += (long)B * H * L * DK;
    float* kb = w;        w += (long)B * H * L * DK;
    float* vb = w;        w += (long)B * H * L * DK;
    float* attnout = w;   w += (long)B * L * DM;
    float* hp = w;        w += (long)B * L * DIM;

    // ---- GNN ----
    k_embed_fp<<<(B * N * DIM + 255) / 256, 256, 0, stream>>>(fingerprints, emb_fp, xs);
    for (int i = 0; i < LG; i++) {
        k_gnn_h<<<(B * N + 255) / 256, 256, 0, stream>>>(
            xs, fp_mask, Wg + i * DIM * DIM, bg + i * DIM, attn_a + i * 2 * DIM, h, s1, s2);
        k_gnn_att<<<B * (N / 16), 256, 0, stream>>>(h, s1, s2, adjacency, xs);
    }
    k_compound<<<B, 256, 0, stream>>>(xs, fp_mask, Watt, batt, compound, hc);

    // ---- Transformer ----
    k_pe<<<(L * DM + 255) / 256, 256, 0, stream>>>(pe);
    k_embed_word<<<(B * L * DM + 255) / 256, 256, 0, stream>>>(words, emb_word, pe, x);
    k_layernorm<<<B * L, DM, 0, stream>>>(x, ln1_g, ln1_b, xn);
    k_qkv<<<B * L / RF, 3 * DM, 0, stream>>>(xn, Wq, bq, Wk, bk, Wv, bv, qb, kb, vb);
    k_attn<<<B * H * (L / AQR), 256, 0, stream>>>(qb, kb, vb, words_mask, attnout);
    k_oproj<<<B * L / RF, DM, 0, stream>>>(attnout, Wo, bo, x);
    k_layernorm<<<B * L, DM, 0, stream>>>(x, ln2_g, ln2_b, xn);
    k_ffn<<<B * L / RF, DFF, 0, stream>>>(xn, W1, b1, W2, b2, x);
    k_lnf_hp<<<B * L, DM, 0, stream>>>(x, lnf_g, lnf_b, Wtout, btout, Watt, batt, hp);
    k_final<<<B, 256, 0, stream>>>(hp, hc, compound, Wout, bout, Wint, bint, out);
}

// Round 3
// 391.325 us; speedup vs baseline: 1.4929x; 1.4929x over previous
//
#include <hip/hip_runtime.h>
#include <hip/hip_bf16.h>
#include <math.h>

#define B 16
#define N 512
#define L 512
#define DIM 10
#define DM 128
#define H 8
#define DK 16
#define DFF 512
#define LG 3
#define LO 3
#define NEGV -9.0e15f
#define RF 16     // rows per block (ffn/qkv/oproj)
#define AQR 64    // q-rows per attn block

__device__ __forceinline__ float wave_reduce_sum(float v) {
    #pragma unroll
    for (int o = 32; o > 0; o >>= 1) v += __shfl_down(v, o, 64);
    return v;
}

// ---------------- GNN ----------------

__global__ void k_embed_fp(const int* __restrict__ fing, const float* __restrict__ emb_fp,
                           float* __restrict__ xs) {
    int idx = blockIdx.x * blockDim.x + threadIdx.x;
    if (idx >= B * N * DIM) return;
    int d = idx % DIM;
    int bn = idx / DIM;
    xs[idx] = emb_fp[fing[bn] * DIM + d];
}

__global__ void k_gnn_h(const float* __restrict__ xs, const float* __restrict__ fp_mask,
                        const float* __restrict__ Wg, const float* __restrict__ bg,
                        const float* __restrict__ aatt,
                        float* __restrict__ h, float* __restrict__ s1, float* __restrict__ s2) {
    int bn = blockIdx.x * blockDim.x + threadIdx.x;
    if (bn >= B * N) return;
    float x[DIM];
    #pragma unroll
    for (int d = 0; d < DIM; d++) x[d] = xs[bn * DIM + d];
    float m = fp_mask[bn];
    float a1 = 0.f, a2 = 0.f;
    #pragma unroll
    for (int j = 0; j < DIM; j++) {
        float acc = bg[j];
        #pragma unroll
        for (int d = 0; d < DIM; d++) acc += x[d] * Wg[d * DIM + j];
        acc = fmaxf(acc, 0.f) * m;
        h[bn * DIM + j] = acc;
        a1 += acc * aatt[j];
        a2 += acc * aatt[DIM + j];
    }
    s1[bn] = a1;
    s2[bn] = a2;
}

// 16 lane-groups of 16 lanes; each group owns one row. grid = B*(N/16), 256 thr.
__global__ void k_gnn_att(const float* __restrict__ h, const float* __restrict__ s1,
                          const float* __restrict__ s2, const int* __restrict__ adj,
                          float* __restrict__ xs) {
    int b  = blockIdx.x / (N / 16);
    int rg = blockIdx.x % (N / 16);
    int t = threadIdx.x;
    int g  = t >> 4;   // group 0..15
    int ll = t & 15;   // lane in group
    int i = rg * 16 + g;

    __shared__ float h_s[N * DIM];   // 20KB
    __shared__ float s2_s[N];        // 2KB

    const float* hb = h + (long)b * N * DIM;
    for (int idx = t; idx < N * DIM; idx += 256) h_s[idx] = hb[idx];
    for (int j = t; j < N; j += 256) s2_s[j] = s2[b * N + j];
    __syncthreads();

    float s1v = s1[b * N + i];
    const int* adjrow = adj + ((long)b * N + i) * N;

    float e[32];
    #pragma unroll
    for (int c = 0; c < 32; c++) {
        int j = c * 16 + ll;
        float xsc = s1v + s2_s[j];
        xsc = xsc > 0.f ? xsc : 0.01f * xsc;
        e[c] = (adjrow[j] > 0) ? xsc : NEGV;
    }
    float m = e[0];
    #pragma unroll
    for (int c = 1; c < 32; c++) m = fmaxf(m, e[c]);
    #pragma unroll
    for (int off = 1; off < 16; off <<= 1) m = fmaxf(m, __shfl_xor(m, off, 64));

    float sum = 0.f;
    float a[DIM];
    #pragma unroll
    for (int d = 0; d < DIM; d++) a[d] = 0.f;
    #pragma unroll
    for (int c = 0; c < 32; c++) {
        float p = expf(e[c] - m);
        sum += p;
        int j = c * 16 + ll;
        #pragma unroll
        for (int d = 0; d < DIM; d++) a[d] += p * h_s[j * DIM + d];
    }
    #pragma unroll
    for (int off = 1; off < 16; off <<= 1) {
        sum += __shfl_xor(sum, off, 64);
        #pragma unroll
        for (int d = 0; d < DIM; d++) a[d] += __shfl_xor(a[d], off, 64);
    }
    if (ll < DIM) {
        float av = a[0];
        if (ll == 1) av = a[1]; else if (ll == 2) av = a[2]; else if (ll == 3) av = a[3];
        else if (ll == 4) av = a[4]; else if (ll == 5) av = a[5]; else if (ll == 6) av = a[6];
        else if (ll == 7) av = a[7]; else if (ll == 8) av = a[8]; else if (ll == 9) av = a[9];
        xs[((long)b * N + i) * DIM + ll] += av / sum;
    }
}

__global__ void k_compound(const float* __restrict__ xs, const float* __restrict__ fp_mask,
                           const float* __restrict__ Watt, const float* __restrict__ batt,
                           float* __restrict__ compound, float* __restrict__ hc) {
    int b = blockIdx.x;
    int t = threadIdx.x;  // 256
    int wid = t >> 6, lane = t & 63;
    float lacc[DIM];
    #pragma unroll
    for (int d = 0; d < DIM; d++) lacc[d] = 0.f;
    for (int n = t; n < N; n += 256) {
        float m = fp_mask[b * N + n];
        #pragma unroll
        for (int d = 0; d < DIM; d++) lacc[d] += xs[((long)b * N + n) * DIM + d] * m;
    }
    __shared__ float red[4][DIM];
    __shared__ float comp_s[DIM];
    #pragma unroll
    for (int d = 0; d < DIM; d++) lacc[d] = wave_reduce_sum(lacc[d]);
    if (lane == 0) {
        #pragma unroll
        for (int d = 0; d < DIM; d++) red[wid][d] = lacc[d];
    }
    __syncthreads();
    if (t < DIM) {
        float c = (red[0][t] + red[1][t] + red[2][t] + red[3][t]) / (float)N;
        compound[b * DIM + t] = c;
        comp_s[t] = c;
    }
    __syncthreads();
    if (t < DIM) {
        float acc = batt[t];
        #pragma unroll
        for (int e = 0; e < DIM; e++) acc += comp_s[e] * Watt[e * DIM + t];
        hc[b * DIM + t] = fmaxf(acc, 0.f);
    }
}

// ---------------- Transformer ----------------

__global__ void k_pe(float* __restrict__ pe) {
    int idx = blockIdx.x * blockDim.x + threadIdx.x;
    if (idx >= L * DM) return;
    int d = idx % DM, l = idx / DM;
    int k = d >> 1;
    double div = exp((double)(2 * k) * (-log(10000.0) / (double)DM));
    double ang = (double)l * div;
    pe[idx] = (d & 1) ? (float)cos(ang) : (float)sin(ang);
}

__global__ void k_embed_word(const int* __restrict__ words, const float* __restrict__ emb,
                             const float* __restrict__ pe, float* __restrict__ x) {
    long idx = (long)blockIdx.x * blockDim.x + threadIdx.x;
    if (idx >= (long)B * L * DM) return;
    int d = idx % DM;
    long bl = idx / DM;
    int l = (int)(bl % L);
    x[idx] = emb[(long)words[bl] * DM + d] * sqrtf(128.0f) + pe[l * DM + d];
}

__global__ void k_layernorm(const float* __restrict__ x, const float* __restrict__ g,
                            const float* __restrict__ bb, float* __restrict__ out) {
    int row = blockIdx.x;
    int t = threadIdx.x;  // 128
    int wid = t >> 6, lane = t & 63;
    float v = x[(long)row * DM + t];
    float s = wave_reduce_sum(v);
    __shared__ float r2[2], r3[2];
    if (lane == 0) r2[wid] = s;
    __syncthreads();
    float mean = (r2[0] + r2[1]) / (float)DM;
    float dv = v - mean;
    float q = wave_reduce_sum(dv * dv);
    if (lane == 0) r3[wid] = q;
    __syncthreads();
    float sd = sqrtf((r3[0] + r3[1]) / (float)(DM - 1)) + 1e-6f;
    out[(long)row * DM + t] = g[t] * dv / sd + bb[t];
}

// 16 rows per block, 384 threads: thread = (proj, out-col)
__global__ void k_qkv(const float* __restrict__ xn,
                      const float* __restrict__ Wq, const float* __restrict__ bq,
                      const float* __restrict__ Wk, const float* __restrict__ bk,
                      const float* __restrict__ Wv, const float* __restrict__ bv,
                      float* __restrict__ q, float* __restrict__ k, float* __restrict__ v) {
    long row0 = (long)blockIdx.x * RF;
    int t = threadIdx.x;  // 384
    __shared__ float xs_s[RF * DM];
    for (int i = t; i < RF * DM; i += 384) xs_s[i] = xn[row0 * DM + i];
    __syncthreads();
    int proj = t / DM;
    int j = t % DM;
    const float* W    = proj == 0 ? Wq : (proj == 1 ? Wk : Wv);
    const float* bias = proj == 0 ? bq : (proj == 1 ? bk : bv);
    float* out        = proj == 0 ? q  : (proj == 1 ? k  : v);
    float acc[RF];
    #pragma unroll
    for (int r = 0; r < RF; r++) acc[r] = bias[j];
    for (int d = 0; d < DM; d++) {
        float w = W[d * DM + j];
        #pragma unroll
        for (int r = 0; r < RF; r++) acc[r] += xs_s[r * DM + d] * w;
    }
    #pragma unroll
    for (int r = 0; r < RF; r++) {
        long row = row0 + r;
        int b = (int)(row / L), l = (int)(row % L);
        out[(((long)b * H + j / DK) * L + l) * DK + (j % DK)] = acc[r];
    }
}

// dim-sliced flash attention. grid = B*H*(L/AQR), 256 threads.
// thread: sl = t&3 (owns q/out float4 slice), r = t>>2 (q-row in block).
// Softmax state (m, ssum) replicated across the 4 slice-lanes via shfl-combined
// scores -> no spill (12 persistent regs), no final merge.
__global__ void k_attn(const float* __restrict__ q, const float* __restrict__ k,
                       const float* __restrict__ v, const float* __restrict__ wmask,
                       float* __restrict__ attnout) {
    int blk = blockIdx.x;
    int qc = blk % (L / AQR);
    int bh = blk / (L / AQR);
    int b = bh / H, hh = bh % H;
    int t = threadIdx.x;   // 256
    int sl = t & 3;
    int r = t >> 2;
    int l = qc * AQR + r;

    __shared__ float4 k_s[L * 4];   // 32KB
    __shared__ float wm_s[L];       // 2KB
    const float4* kb4 = (const float4*)(k + (long)bh * L * DK);
    for (int i = t; i < L * 4; i += 256) k_s[i] = kb4[i];
    for (int j = t; j < L; j += 256) wm_s[j] = wmask[b * L + j];
    __syncthreads();

    float4 qr = ((const float4*)(q + ((long)bh * L + l) * DK))[sl];
    qr.x *= 0.25f; qr.y *= 0.25f; qr.z *= 0.25f; qr.w *= 0.25f;

    const float4* vb4 = (const float4*)(v + (long)bh * L * DK);

    float m = -1e30f, ssum = 0.f;
    float4 acc = make_float4(0.f, 0.f, 0.f, 0.f);

    for (int c = 0; c < L / 8; c++) {
        int j0 = c * 8;
        float s8[8];
        // partial dot over this lane's 4 dims
        #pragma unroll
        for (int jj = 0; jj < 8; jj++) {
            float4 kk = k_s[(j0 + jj) * 4 + sl];
            s8[jj] = qr.x * kk.x + qr.y * kk.y + qr.z * kk.z + qr.w * kk.w;
        }
        // combine 4 slices (lanes differing in bits 0-1)
        #pragma unroll
        for (int jj = 0; jj < 8; jj++) {
            s8[jj] += __shfl_xor(s8[jj], 1, 64);
            s8[jj] += __shfl_xor(s8[jj], 2, 64);
            s8[jj] = (wm_s[j0 + jj] > 0.f) ? s8[jj] : -1e9f;
        }
        float cm = fmaxf(fmaxf(fmaxf(s8[0], s8[1]), fmaxf(s8[2], s8[3])),
                         fmaxf(fmaxf(s8[4], s8[5]), fmaxf(s8[6], s8[7])));
        float mn = fmaxf(m, cm);
        float scale = __expf(m - mn);
        ssum *= scale;
        acc.x *= scale; acc.y *= scale; acc.z *= scale; acc.w *= scale;
        #pragma unroll
        for (int jj = 0; jj < 8; jj++) {
            float p = __expf(s8[jj] - mn);
            ssum += p;
            float4 vv = vb4[(j0 + jj) * 4 + sl];
            acc.x += p * vv.x; acc.y += p * vv.y; acc.z += p * vv.z; acc.w += p * vv.w;
        }
        m = mn;
    }

    float inv = 1.f / ssum;
    float4* outp = (float4*)(attnout + ((long)b * L + l) * DM + hh * DK);
    outp[sl] = make_float4(acc.x * inv, acc.y * inv, acc.z * inv, acc.w * inv);
}

// x += attnout @ Wo + bo ; 16 rows/block, 128 threads
__global__ void k_oproj(const float* __restrict__ attnout, const float* __restrict__ Wo,
                        const float* __restrict__ bo, float* __restrict__ x) {
    long row0 = (long)blockIdx.x * RF;
    int t = threadIdx.x;  // 128
    __shared__ float a_s[RF * DM];
    for (int i = t; i < RF * DM; i += 128) a_s[i] = attnout[row0 * DM + i];
    __syncthreads();
    float acc[RF];
    #pragma unroll
    for (int r = 0; r < RF; r++) acc[r] = bo[t];
    for (int d = 0; d < DM; d++) {
        float w = Wo[d * DM + t];
        #pragma unroll
        for (int r = 0; r < RF; r++) acc[r] += a_s[r * DM + d] * w;
    }
    #pragma unroll
    for (int r = 0; r < RF; r++) x[(row0 + r) * DM + t] += acc[r];
}

// fused FFN: x += relu(xn@W1+b1)@W2+b2 ; 16 rows/block, 512 threads
__global__ void k_ffn(const float* __restrict__ xn, const float* __restrict__ W1,
                      const float* __restrict__ b1, const float* __restrict__ W2,
                      const float* __restrict__ b2, float* __restrict__ x) {
    long row0 = (long)blockIdx.x * RF;
    int t = threadIdx.x;  // 512
    __shared__ float xs_s[RF * DM];    // 8KB
    __shared__ float h_s[RF * DFF];    // 32KB
    for (int i = t; i < RF * DM; i += 512) xs_s[i] = xn[row0 * DM + i];
    __syncthreads();
    {
        float acc[RF];
        #pragma unroll
        for (int r = 0; r < RF; r++) acc[r] = b1[t];
        for (int d = 0; d < DM; d++) {
            float w = W1[d * DFF + t];
            #pragma unroll
            for (int r = 0; r < RF; r++) acc[r] += xs_s[r * DM + d] * w;
        }
        #pragma unroll
        for (int r = 0; r < RF; r++) h_s[r * DFF + t] = fmaxf(acc[r], 0.f);
    }
    __syncthreads();
    int col = t & 127, rq = t >> 7;   // rq uniform per wave
    float acc2[4];
    #pragma unroll
    for (int rr = 0; rr < 4; rr++) acc2[rr] = b2[col];
    for (int f = 0; f < DFF; f++) {
        float w = W2[f * DM + col];
        #pragma unroll
        for (int rr = 0; rr < 4; rr++) acc2[rr] += h_s[(rq * 4 + rr) * DFF + f] * w;
    }
    #pragma unroll
    for (int rr = 0; rr < 4; rr++) x[(row0 + rq * 4 + rr) * DM + col] += acc2[rr];
}

// lnf -> relu -> Wtout -> Watt/relu -> hp ; per row, 128 threads
__global__ void k_lnf_hp(const float* __restrict__ x, const float* __restrict__ g,
                         const float* __restrict__ bb, const float* __restrict__ Wtout,
                         const float* __restrict__ btout, const float* __restrict__ Watt,
                         const float* __restrict__ batt, float* __restrict__ hp) {
    int row = blockIdx.x;
    int t = threadIdx.x;  // 128
    int wid = t >> 6, lane = t & 63;
    float v = x[(long)row * DM + t];
    float s = wave_reduce_sum(v);
    __shared__ float r2[2], r3[2];
    if (lane == 0) r2[wid] = s;
    __syncthreads();
    float mean = (r2[0] + r2[1]) / (float)DM;
    float dv = v - mean;
    float qq = wave_reduce_sum(dv * dv);
    if (lane == 0) r3[wid] = qq;
    __syncthreads();
    float sd = sqrtf((r3[0] + r3[1]) / (float)(DM - 1)) + 1e-6f;
    float xnv = g[t] * dv / sd + bb[t];
    __shared__ float rrelu[DM];
    rrelu[t] = fmaxf(xnv, 0.f);
    __syncthreads();
    __shared__ float wv_s[DIM];
    if (t < DIM) {
        float acc = btout[t];
        for (int d = 0; d < DM; d++) acc += rrelu[d] * Wtout[d * DIM + t];
        wv_s[t] = acc;
    }
    __syncthreads();
    if (t < DIM) {
        float acc = batt[t];
        #pragma unroll
        for (int e = 0; e < DIM; e++) acc += wv_s[e] * Watt[e * DIM + t];
        hp[(long)row * DIM + t] = fmaxf(acc, 0.f);
    }
}

__global__ void k_final(const float* __restrict__ hp, const float* __restrict__ hc,
                        const float* __restrict__ compound, const float* __restrict__ Wout,
                        const float* __restrict__ bout, const float* __restrict__ Wint,
                        const float* __restrict__ bint, float* __restrict__ out) {
    int b = blockIdx.x;
    int t = threadIdx.x;  // 256
    int wid = t >> 6, lane = t & 63;
    __shared__ float hc_s[DIM];
    if (t < DIM) hc_s[t] = hc[b * DIM + t];
    __syncthreads();
    float lacc[DIM];
    #pragma unroll
    for (int e = 0; e < DIM; e++) lacc[e] = 0.f;
    for (int l = t; l < L; l += 256) {
        const float* hpl = hp + ((long)b * L + l) * DIM;
        float hv[DIM];
        float dot = 0.f;
        #pragma unroll
        for (int e = 0; e < DIM; e++) { hv[e] = hpl[e]; dot += hc_s[e] * hv[e]; }
        float w = tanhf(dot);
        #pragma unroll
        for (int e = 0; e < DIM; e++) lacc[e] += w * hv[e];
    }
    __shared__ float red[4][DIM];
    #pragma unroll
    for (int e = 0; e < DIM; e++) lacc[e] = wave_reduce_sum(lacc[e]);
    if (lane == 0) {
        #pragma unroll
        for (int e = 0; e < DIM; e++) red[wid][e] = lacc[e];
    }
    __syncthreads();
    if (t == 0) {
        float cat[2 * DIM], tmp[2 * DIM];
        for (int e = 0; e < DIM; e++) cat[e] = compound[b * DIM + e];
        for (int e = 0; e < DIM; e++)
            cat[DIM + e] = (red[0][e] + red[1][e] + red[2][e] + red[3][e]) / (float)L;
        for (int j = 0; j < LO; j++) {
            const float* W = Wout + j * 2 * DIM * 2 * DIM;
            const float* bj = bout + j * 2 * DIM;
            for (int o = 0; o < 2 * DIM; o++) {
                float acc = bj[o];
                for (int e = 0; e < 2 * DIM; e++) acc += cat[e] * W[e * 2 * DIM + o];
                tmp[o] = fmaxf(acc, 0.f);
            }
            for (int o = 0; o < 2 * DIM; o++) cat[o] = tmp[o];
        }
        float o0 = bint[0], o1 = bint[1];
        for (int e = 0; e < 2 * DIM; e++) {
            o0 += cat[e] * Wint[e * 2 + 0];
            o1 += cat[e] * Wint[e * 2 + 1];
        }
        out[b * 2 + 0] = o0;
        out[b * 2 + 1] = o1;
    }
}

extern "C" void kernel_launch(void* const* d_in, const int* in_sizes, int n_in,
                              void* d_out, int out_size, void* d_ws, size_t ws_size,
                              hipStream_t stream) {
    (void)in_sizes; (void)n_in; (void)out_size; (void)ws_size;
    const int*   fingerprints = (const int*)d_in[0];
    const float* fp_mask      = (const float*)d_in[1];
    const int*   adjacency    = (const int*)d_in[2];
    const int*   words        = (const int*)d_in[3];
    const float* words_mask   = (const float*)d_in[4];
    const float* emb_fp       = (const float*)d_in[5];
    const float* emb_word     = (const float*)d_in[6];
    const float* Wg   = (const float*)d_in[7];
    const float* bg   = (const float*)d_in[8];
    const float* attn_a = (const float*)d_in[9];
    const float* Wq = (const float*)d_in[10];
    const float* bq = (const float*)d_in[11];
    const float* Wk = (const float*)d_in[12];
    const float* bk = (const float*)d_in[13];
    const float* Wv = (const float*)d_in[14];
    const float* bv = (const float*)d_in[15];
    const float* Wo = (const float*)d_in[16];
    const float* bo = (const float*)d_in[17];
    const float* ln1_g = (const float*)d_in[18];
    const float* ln1_b = (const float*)d_in[19];
    const float* ln2_g = (const float*)d_in[20];
    const float* ln2_b = (const float*)d_in[21];
    const float* lnf_g = (const float*)d_in[22];
    const float* lnf_b = (const float*)d_in[23];
    const float* W1 = (const float*)d_in[24];
    const float* b1 = (const float*)d_in[25];
    const float* W2 = (const float*)d_in[26];
    const float* b2 = (const float*)d_in[27];
    const float* Wtout = (const float*)d_in[28];
    const float* btout = (const float*)d_in[29];
    const float* Watt  = (const float*)d_in[30];
    const float* batt  = (const float*)d_in[31];
    const float* Wout  = (const float*)d_in[32];
    const float* bout  = (const float*)d_in[33];
    const float* Wint  = (const float*)d_in[34];
    const float* bint  = (const float*)d_in[35];
    float* out = (float*)d_out;

    float* w = (float*)d_ws;
    float* xs = w;        w += B * N * DIM;
    float* h  = w;        w += B * N * DIM;
    float* s1 = w;        w += B * N;
    float* s2 = w;        w += B * N;
    float* compound = w;  w += B * DIM;
    float* hc = w;        w += B * DIM;
    float* pe = w;        w += L * DM;
    float* x  = w;        w += (long)B * L * DM;
    float* xn = w;        w += (long)B * L * DM;
    float* qb = w;        w += (long)B * H * L * DK;
    float* kb = w;        w += (long)B * H * L * DK;
    float* vb = w;        w += (long)B * H * L * DK;
    float* attnout = w;   w += (long)B * L * DM;
    float* hp = w;        w += (long)B * L * DIM;

    // ---- GNN ----
    k_embed_fp<<<(B * N * DIM + 255) / 256, 256, 0, stream>>>(fingerprints, emb_fp, xs);
    for (int i = 0; i < LG; i++) {
        k_gnn_h<<<(B * N + 255) / 256, 256, 0, stream>>>(
            xs, fp_mask, Wg + i * DIM * DIM, bg + i * DIM, attn_a + i * 2 * DIM, h, s1, s2);
        k_gnn_att<<<B * (N / 16), 256, 0, stream>>>(h, s1, s2, adjacency, xs);
    }
    k_compound<<<B, 256, 0, stream>>>(xs, fp_mask, Watt, batt, compound, hc);

    // ---- Transformer ----
    k_pe<<<(L * DM + 255) / 256, 256, 0, stream>>>(pe);
    k_embed_word<<<(B * L * DM + 255) / 256, 256, 0, stream>>>(words, emb_word, pe, x);
    k_layernorm<<<B * L, DM, 0, stream>>>(x, ln1_g, ln1_b, xn);
    k_qkv<<<B * L / RF, 3 * DM, 0, stream>>>(xn, Wq, bq, Wk, bk, Wv, bv, qb, kb, vb);
    k_attn<<<B * H * (L / AQR), 256, 0, stream>>>(qb, kb, vb, words_mask, attnout);
    k_oproj<<<B * L / RF, DM, 0, stream>>>(attnout, Wo, bo, x);
    k_layernorm<<<B * L, DM, 0, stream>>>(x, ln2_g, ln2_b, xn);
    k_ffn<<<B * L / RF, DFF, 0, stream>>>(xn, W1, b1, W2, b2, x);
    k_lnf_hp<<<B * L, DM, 0, stream>>>(x, lnf_g, lnf_b, Wtout, btout, Watt, batt, hp);
    k_final<<<B, 256, 0, stream>>>(hp, hc, compound, Wout, bout, Wint, bint, out);
}

// Round 4
// 277.088 us; speedup vs baseline: 2.1084x; 1.4123x over previous
//
#include <hip/hip_runtime.h>
#include <hip/hip_bf16.h>
#include <math.h>

#define B 16
#define N 512
#define L 512
#define DIM 10
#define DM 128
#define H 8
#define DK 16
#define DFF 512
#define LG 3
#define LO 3
#define NEGV -9.0e15f
#define RF 16     // rows per block (ffn/qkv/oproj)
#define AQR 64    // q-rows per attn block

__device__ __forceinline__ float wave_reduce_sum(float v) {
    #pragma unroll
    for (int o = 32; o > 0; o >>= 1) v += __shfl_down(v, o, 64);
    return v;
}

// ---------------- GNN ----------------

__global__ void k_embed_fp(const int* __restrict__ fing, const float* __restrict__ emb_fp,
                           float* __restrict__ xs) {
    int idx = blockIdx.x * blockDim.x + threadIdx.x;
    if (idx >= B * N * DIM) return;
    int d = idx % DIM;
    int bn = idx / DIM;
    xs[idx] = emb_fp[fing[bn] * DIM + d];
}

__global__ void k_gnn_h(const float* __restrict__ xs, const float* __restrict__ fp_mask,
                        const float* __restrict__ Wg, const float* __restrict__ bg,
                        const float* __restrict__ aatt,
                        float* __restrict__ h, float* __restrict__ s1, float* __restrict__ s2) {
    int bn = blockIdx.x * blockDim.x + threadIdx.x;
    if (bn >= B * N) return;
    float x[DIM];
    #pragma unroll
    for (int d = 0; d < DIM; d++) x[d] = xs[bn * DIM + d];
    float m = fp_mask[bn];
    float a1 = 0.f, a2 = 0.f;
    #pragma unroll
    for (int j = 0; j < DIM; j++) {
        float acc = bg[j];
        #pragma unroll
        for (int d = 0; d < DIM; d++) acc += x[d] * Wg[d * DIM + j];
        acc = fmaxf(acc, 0.f) * m;
        h[bn * DIM + j] = acc;
        a1 += acc * aatt[j];
        a2 += acc * aatt[DIM + j];
    }
    s1[bn] = a1;
    s2[bn] = a2;
}

// 16 lane-groups of 16 lanes; each group owns one row. grid = B*(N/16), 256 thr.
__global__ void k_gnn_att(const float* __restrict__ h, const float* __restrict__ s1,
                          const float* __restrict__ s2, const int* __restrict__ adj,
                          float* __restrict__ xs) {
    int b  = blockIdx.x / (N / 16);
    int rg = blockIdx.x % (N / 16);
    int t = threadIdx.x;
    int g  = t >> 4;   // group 0..15
    int ll = t & 15;   // lane in group
    int i = rg * 16 + g;

    __shared__ float h_s[N * DIM];   // 20KB
    __shared__ float s2_s[N];        // 2KB

    const float* hb = h + (long)b * N * DIM;
    for (int idx = t; idx < N * DIM; idx += 256) h_s[idx] = hb[idx];
    for (int j = t; j < N; j += 256) s2_s[j] = s2[b * N + j];
    __syncthreads();

    float s1v = s1[b * N + i];
    const int* adjrow = adj + ((long)b * N + i) * N;

    float e[32];
    #pragma unroll
    for (int c = 0; c < 32; c++) {
        int j = c * 16 + ll;
        float xsc = s1v + s2_s[j];
        xsc = xsc > 0.f ? xsc : 0.01f * xsc;
        e[c] = (adjrow[j] > 0) ? xsc : NEGV;
    }
    float m = e[0];
    #pragma unroll
    for (int c = 1; c < 32; c++) m = fmaxf(m, e[c]);
    #pragma unroll
    for (int off = 1; off < 16; off <<= 1) m = fmaxf(m, __shfl_xor(m, off, 64));

    float sum = 0.f;
    float a[DIM];
    #pragma unroll
    for (int d = 0; d < DIM; d++) a[d] = 0.f;
    #pragma unroll
    for (int c = 0; c < 32; c++) {
        float p = expf(e[c] - m);
        sum += p;
        int j = c * 16 + ll;
        #pragma unroll
        for (int d = 0; d < DIM; d++) a[d] += p * h_s[j * DIM + d];
    }
    #pragma unroll
    for (int off = 1; off < 16; off <<= 1) {
        sum += __shfl_xor(sum, off, 64);
        #pragma unroll
        for (int d = 0; d < DIM; d++) a[d] += __shfl_xor(a[d], off, 64);
    }
    if (ll < DIM) {
        float av = a[0];
        if (ll == 1) av = a[1]; else if (ll == 2) av = a[2]; else if (ll == 3) av = a[3];
        else if (ll == 4) av = a[4]; else if (ll == 5) av = a[5]; else if (ll == 6) av = a[6];
        else if (ll == 7) av = a[7]; else if (ll == 8) av = a[8]; else if (ll == 9) av = a[9];
        xs[((long)b * N + i) * DIM + ll] += av / sum;
    }
}

__global__ void k_compound(const float* __restrict__ xs, const float* __restrict__ fp_mask,
                           const float* __restrict__ Watt, const float* __restrict__ batt,
                           float* __restrict__ compound, float* __restrict__ hc) {
    int b = blockIdx.x;
    int t = threadIdx.x;  // 256
    int wid = t >> 6, lane = t & 63;
    float lacc[DIM];
    #pragma unroll
    for (int d = 0; d < DIM; d++) lacc[d] = 0.f;
    for (int n = t; n < N; n += 256) {
        float m = fp_mask[b * N + n];
        #pragma unroll
        for (int d = 0; d < DIM; d++) lacc[d] += xs[((long)b * N + n) * DIM + d] * m;
    }
    __shared__ float red[4][DIM];
    __shared__ float comp_s[DIM];
    #pragma unroll
    for (int d = 0; d < DIM; d++) lacc[d] = wave_reduce_sum(lacc[d]);
    if (lane == 0) {
        #pragma unroll
        for (int d = 0; d < DIM; d++) red[wid][d] = lacc[d];
    }
    __syncthreads();
    if (t < DIM) {
        float c = (red[0][t] + red[1][t] + red[2][t] + red[3][t]) / (float)N;
        compound[b * DIM + t] = c;
        comp_s[t] = c;
    }
    __syncthreads();
    if (t < DIM) {
        float acc = batt[t];
        #pragma unroll
        for (int e = 0; e < DIM; e++) acc += comp_s[e] * Watt[e * DIM + t];
        hc[b * DIM + t] = fmaxf(acc, 0.f);
    }
}

// ---------------- Transformer ----------------

__global__ void k_pe(float* __restrict__ pe) {
    int idx = blockIdx.x * blockDim.x + threadIdx.x;
    if (idx >= L * DM) return;
    int d = idx % DM, l = idx / DM;
    int k = d >> 1;
    double div = exp((double)(2 * k) * (-log(10000.0) / (double)DM));
    double ang = (double)l * div;
    pe[idx] = (d & 1) ? (float)cos(ang) : (float)sin(ang);
}

__global__ void k_embed_word(const int* __restrict__ words, const float* __restrict__ emb,
                             const float* __restrict__ pe, float* __restrict__ x) {
    long idx = (long)blockIdx.x * blockDim.x + threadIdx.x;
    if (idx >= (long)B * L * DM) return;
    int d = idx % DM;
    long bl = idx / DM;
    int l = (int)(bl % L);
    x[idx] = emb[(long)words[bl] * DM + d] * sqrtf(128.0f) + pe[l * DM + d];
}

__global__ void k_layernorm(const float* __restrict__ x, const float* __restrict__ g,
                            const float* __restrict__ bb, float* __restrict__ out) {
    int row = blockIdx.x;
    int t = threadIdx.x;  // 128
    int wid = t >> 6, lane = t & 63;
    float v = x[(long)row * DM + t];
    float s = wave_reduce_sum(v);
    __shared__ float r2[2], r3[2];
    if (lane == 0) r2[wid] = s;
    __syncthreads();
    float mean = (r2[0] + r2[1]) / (float)DM;
    float dv = v - mean;
    float q = wave_reduce_sum(dv * dv);
    if (lane == 0) r3[wid] = q;
    __syncthreads();
    float sd = sqrtf((r3[0] + r3[1]) / (float)(DM - 1)) + 1e-6f;
    out[(long)row * DM + t] = g[t] * dv / sd + bb[t];
}

// 16 rows per block, 384 threads: thread = (proj, out-col)
__global__ void k_qkv(const float* __restrict__ xn,
                      const float* __restrict__ Wq, const float* __restrict__ bq,
                      const float* __restrict__ Wk, const float* __restrict__ bk,
                      const float* __restrict__ Wv, const float* __restrict__ bv,
                      float* __restrict__ q, float* __restrict__ k, float* __restrict__ v) {
    long row0 = (long)blockIdx.x * RF;
    int t = threadIdx.x;  // 384
    __shared__ float xs_s[RF * DM];
    for (int i = t; i < RF * DM; i += 384) xs_s[i] = xn[row0 * DM + i];
    __syncthreads();
    int proj = t / DM;
    int j = t % DM;
    const float* W    = proj == 0 ? Wq : (proj == 1 ? Wk : Wv);
    const float* bias = proj == 0 ? bq : (proj == 1 ? bk : bv);
    float* out        = proj == 0 ? q  : (proj == 1 ? k  : v);
    float acc[RF];
    #pragma unroll
    for (int r = 0; r < RF; r++) acc[r] = bias[j];
    for (int d = 0; d < DM; d++) {
        float w = W[d * DM + j];
        #pragma unroll
        for (int r = 0; r < RF; r++) acc[r] += xs_s[r * DM + d] * w;
    }
    #pragma unroll
    for (int r = 0; r < RF; r++) {
        long row = row0 + r;
        int b = (int)(row / L), l = (int)(row % L);
        out[(((long)b * H + j / DK) * L + l) * DK + (j % DK)] = acc[r];
    }
}

// dim-sliced flash attention. grid = B*H*(L/AQR), 256 threads.
__global__ void k_attn(const float* __restrict__ q, const float* __restrict__ k,
                       const float* __restrict__ v, const float* __restrict__ wmask,
                       float* __restrict__ attnout) {
    int blk = blockIdx.x;
    int qc = blk % (L / AQR);
    int bh = blk / (L / AQR);
    int b = bh / H, hh = bh % H;
    int t = threadIdx.x;   // 256
    int sl = t & 3;
    int r = t >> 2;
    int l = qc * AQR + r;

    __shared__ float4 k_s[L * 4];   // 32KB
    __shared__ float wm_s[L];       // 2KB
    const float4* kb4 = (const float4*)(k + (long)bh * L * DK);
    for (int i = t; i < L * 4; i += 256) k_s[i] = kb4[i];
    for (int j = t; j < L; j += 256) wm_s[j] = wmask[b * L + j];
    __syncthreads();

    float4 qr = ((const float4*)(q + ((long)bh * L + l) * DK))[sl];
    qr.x *= 0.25f; qr.y *= 0.25f; qr.z *= 0.25f; qr.w *= 0.25f;

    const float4* vb4 = (const float4*)(v + (long)bh * L * DK);

    float m = -1e30f, ssum = 0.f;
    float4 acc = make_float4(0.f, 0.f, 0.f, 0.f);

    for (int c = 0; c < L / 8; c++) {
        int j0 = c * 8;
        float s8[8];
        #pragma unroll
        for (int jj = 0; jj < 8; jj++) {
            float4 kk = k_s[(j0 + jj) * 4 + sl];
            s8[jj] = qr.x * kk.x + qr.y * kk.y + qr.z * kk.z + qr.w * kk.w;
        }
        #pragma unroll
        for (int jj = 0; jj < 8; jj++) {
            s8[jj] += __shfl_xor(s8[jj], 1, 64);
            s8[jj] += __shfl_xor(s8[jj], 2, 64);
            s8[jj] = (wm_s[j0 + jj] > 0.f) ? s8[jj] : -1e9f;
        }
        float cm = fmaxf(fmaxf(fmaxf(s8[0], s8[1]), fmaxf(s8[2], s8[3])),
                         fmaxf(fmaxf(s8[4], s8[5]), fmaxf(s8[6], s8[7])));
        float mn = fmaxf(m, cm);
        float scale = __expf(m - mn);
        ssum *= scale;
        acc.x *= scale; acc.y *= scale; acc.z *= scale; acc.w *= scale;
        #pragma unroll
        for (int jj = 0; jj < 8; jj++) {
            float p = __expf(s8[jj] - mn);
            ssum += p;
            float4 vv = vb4[(j0 + jj) * 4 + sl];
            acc.x += p * vv.x; acc.y += p * vv.y; acc.z += p * vv.z; acc.w += p * vv.w;
        }
        m = mn;
    }

    float inv = 1.f / ssum;
    float4* outp = (float4*)(attnout + ((long)b * L + l) * DM + hh * DK);
    outp[sl] = make_float4(acc.x * inv, acc.y * inv, acc.z * inv, acc.w * inv);
}

// x += attnout @ Wo + bo ; 16 rows/block, 128 threads
__global__ void k_oproj(const float* __restrict__ attnout, const float* __restrict__ Wo,
                        const float* __restrict__ bo, float* __restrict__ x) {
    long row0 = (long)blockIdx.x * RF;
    int t = threadIdx.x;  // 128
    __shared__ float a_s[RF * DM];
    for (int i = t; i < RF * DM; i += 128) a_s[i] = attnout[row0 * DM + i];
    __syncthreads();
    float acc[RF];
    #pragma unroll
    for (int r = 0; r < RF; r++) acc[r] = bo[t];
    for (int d = 0; d < DM; d++) {
        float w = Wo[d * DM + t];
        #pragma unroll
        for (int r = 0; r < RF; r++) acc[r] += a_s[r * DM + d] * w;
    }
    #pragma unroll
    for (int r = 0; r < RF; r++) x[(row0 + r) * DM + t] += acc[r];
}

// fused FFN: x += relu(xn@W1+b1)@W2+b2 ; 16 rows/block, 512 threads
__global__ void k_ffn(const float* __restrict__ xn, const float* __restrict__ W1,
                      const float* __restrict__ b1, const float* __restrict__ W2,
                      const float* __restrict__ b2, float* __restrict__ x) {
    long row0 = (long)blockIdx.x * RF;
    int t = threadIdx.x;  // 512
    __shared__ float xs_s[RF * DM];    // 8KB
    __shared__ float h_s[RF * DFF];    // 32KB
    for (int i = t; i < RF * DM; i += 512) xs_s[i] = xn[row0 * DM + i];
    __syncthreads();
    {
        float acc[RF];
        #pragma unroll
        for (int r = 0; r < RF; r++) acc[r] = b1[t];
        for (int d = 0; d < DM; d++) {
            float w = W1[d * DFF + t];
            #pragma unroll
            for (int r = 0; r < RF; r++) acc[r] += xs_s[r * DM + d] * w;
        }
        #pragma unroll
        for (int r = 0; r < RF; r++) h_s[r * DFF + t] = fmaxf(acc[r], 0.f);
    }
    __syncthreads();
    int col = t & 127, rq = t >> 7;   // rq uniform per wave
    float acc2[4];
    #pragma unroll
    for (int rr = 0; rr < 4; rr++) acc2[rr] = b2[col];
    for (int f = 0; f < DFF; f++) {
        float w = W2[f * DM + col];
        #pragma unroll
        for (int rr = 0; rr < 4; rr++) acc2[rr] += h_s[(rq * 4 + rr) * DFF + f] * w;
    }
    #pragma unroll
    for (int rr = 0; rr < 4; rr++) x[(row0 + rq * 4 + rr) * DM + col] += acc2[rr];
}

// lnf -> relu -> Wtout -> Watt/relu -> hp ; per row, 128 threads
__global__ void k_lnf_hp(const float* __restrict__ x, const float* __restrict__ g,
                         const float* __restrict__ bb, const float* __restrict__ Wtout,
                         const float* __restrict__ btout, const float* __restrict__ Watt,
                         const float* __restrict__ batt, float* __restrict__ hp) {
    int row = blockIdx.x;
    int t = threadIdx.x;  // 128
    int wid = t >> 6, lane = t & 63;
    float v = x[(long)row * DM + t];
    float s = wave_reduce_sum(v);
    __shared__ float r2[2], r3[2];
    if (lane == 0) r2[wid] = s;
    __syncthreads();
    float mean = (r2[0] + r2[1]) / (float)DM;
    float dv = v - mean;
    float qq = wave_reduce_sum(dv * dv);
    if (lane == 0) r3[wid] = qq;
    __syncthreads();
    float sd = sqrtf((r3[0] + r3[1]) / (float)(DM - 1)) + 1e-6f;
    float xnv = g[t] * dv / sd + bb[t];
    __shared__ float rrelu[DM];
    rrelu[t] = fmaxf(xnv, 0.f);
    __syncthreads();
    __shared__ float wv_s[DIM];
    if (t < DIM) {
        float acc = btout[t];
        for (int d = 0; d < DM; d++) acc += rrelu[d] * Wtout[d * DIM + t];
        wv_s[t] = acc;
    }
    __syncthreads();
    if (t < DIM) {
        float acc = batt[t];
        #pragma unroll
        for (int e = 0; e < DIM; e++) acc += wv_s[e] * Watt[e * DIM + t];
        hp[(long)row * DIM + t] = fmaxf(acc, 0.f);
    }
}

// final: w = tanh(hc . hp_l) ; protein = mean(w * hp) ; 3-layer MLP ; output.
// MLP parallelized across 2*DIM=20 threads; weights staged in LDS.
__global__ void k_final(const float* __restrict__ hp, const float* __restrict__ hc,
                        const float* __restrict__ compound, const float* __restrict__ Wout,
                        const float* __restrict__ bout, const float* __restrict__ Wint,
                        const float* __restrict__ bint, float* __restrict__ out) {
    int b = blockIdx.x;
    int t = threadIdx.x;  // 256
    int wid = t >> 6, lane = t & 63;

    __shared__ float wout_s[LO * 2 * DIM * 2 * DIM];  // 1200 floats
    __shared__ float bout_s[LO * 2 * DIM];
    __shared__ float wint_s[2 * DIM * 2];
    __shared__ float bint_s[2];
    __shared__ float hc_s[DIM];
    __shared__ float red[4][DIM];
    __shared__ float cat_s[2 * DIM];
    __shared__ float tmp_s[2 * DIM];

    // stage small weights (overlaps with phase-1 latency)
    for (int i = t; i < LO * 2 * DIM * 2 * DIM; i += 256) wout_s[i] = Wout[i];
    for (int i = t; i < LO * 2 * DIM; i += 256) bout_s[i] = bout[i];
    for (int i = t; i < 2 * DIM * 2; i += 256) wint_s[i] = Wint[i];
    if (t < 2) bint_s[t] = bint[t];
    if (t < DIM) hc_s[t] = hc[b * DIM + t];
    __syncthreads();

    float lacc[DIM];
    #pragma unroll
    for (int e = 0; e < DIM; e++) lacc[e] = 0.f;
    for (int l = t; l < L; l += 256) {
        const float* hpl = hp + ((long)b * L + l) * DIM;
        float hv[DIM];
        float dot = 0.f;
        #pragma unroll
        for (int e = 0; e < DIM; e++) { hv[e] = hpl[e]; dot += hc_s[e] * hv[e]; }
        float w = tanhf(dot);
        #pragma unroll
        for (int e = 0; e < DIM; e++) lacc[e] += w * hv[e];
    }
    #pragma unroll
    for (int e = 0; e < DIM; e++) lacc[e] = wave_reduce_sum(lacc[e]);
    if (lane == 0) {
        #pragma unroll
        for (int e = 0; e < DIM; e++) red[wid][e] = lacc[e];
    }
    __syncthreads();
    if (t < DIM) {
        cat_s[t] = compound[b * DIM + t];
        cat_s[DIM + t] = (red[0][t] + red[1][t] + red[2][t] + red[3][t]) / (float)L;
    }
    __syncthreads();

    // 3-layer MLP: 20 threads, one output column each
    for (int j = 0; j < LO; j++) {
        float acc = 0.f;
        if (t < 2 * DIM) {
            acc = bout_s[j * 2 * DIM + t];
            #pragma unroll
            for (int e = 0; e < 2 * DIM; e++)
                acc += cat_s[e] * wout_s[j * 2 * DIM * 2 * DIM + e * 2 * DIM + t];
            acc = fmaxf(acc, 0.f);
            tmp_s[t] = acc;
        }
        __syncthreads();
        if (t < 2 * DIM) cat_s[t] = tmp_s[t];
        __syncthreads();
    }
    if (t < 2) {
        float o = bint_s[t];
        #pragma unroll
        for (int e = 0; e < 2 * DIM; e++) o += cat_s[e] * wint_s[e * 2 + t];
        out[b * 2 + t] = o;
    }
}

extern "C" void kernel_launch(void* const* d_in, const int* in_sizes, int n_in,
                              void* d_out, int out_size, void* d_ws, size_t ws_size,
                              hipStream_t stream) {
    (void)in_sizes; (void)n_in; (void)out_size; (void)ws_size;
    const int*   fingerprints = (const int*)d_in[0];
    const float* fp_mask      = (const float*)d_in[1];
    const int*   adjacency    = (const int*)d_in[2];
    const int*   words        = (const int*)d_in[3];
    const float* words_mask   = (const float*)d_in[4];
    const float* emb_fp       = (const float*)d_in[5];
    const float* emb_word     = (const float*)d_in[6];
    const float* Wg   = (const float*)d_in[7];
    const float* bg   = (const float*)d_in[8];
    const float* attn_a = (const float*)d_in[9];
    const float* Wq = (const float*)d_in[10];
    const float* bq = (const float*)d_in[11];
    const float* Wk = (const float*)d_in[12];
    const float* bk = (const float*)d_in[13];
    const float* Wv = (const float*)d_in[14];
    const float* bv = (const float*)d_in[15];
    const float* Wo = (const float*)d_in[16];
    const float* bo = (const float*)d_in[17];
    const float* ln1_g = (const float*)d_in[18];
    const float* ln1_b = (const float*)d_in[19];
    const float* ln2_g = (const float*)d_in[20];
    const float* ln2_b = (const float*)d_in[21];
    const float* lnf_g = (const float*)d_in[22];
    const float* lnf_b = (const float*)d_in[23];
    const float* W1 = (const float*)d_in[24];
    const float* b1 = (const float*)d_in[25];
    const float* W2 = (const float*)d_in[26];
    const float* b2 = (const float*)d_in[27];
    const float* Wtout = (const float*)d_in[28];
    const float* btout = (const float*)d_in[29];
    const float* Watt  = (const float*)d_in[30];
    const float* batt  = (const float*)d_in[31];
    const float* Wout  = (const float*)d_in[32];
    const float* bout  = (const float*)d_in[33];
    const float* Wint  = (const float*)d_in[34];
    const float* bint  = (const float*)d_in[35];
    float* out = (float*)d_out;

    float* w = (float*)d_ws;
    float* xs = w;        w += B * N * DIM;
    float* h  = w;        w += B * N * DIM;
    float* s1 = w;        w += B * N;
    float* s2 = w;        w += B * N;
    float* compound = w;  w += B * DIM;
    float* hc = w;        w += B * DIM;
    float* pe = w;        w += L * DM;
    float* x  = w;        w += (long)B * L * DM;
    float* xn = w;        w += (long)B * L * DM;
    float* qb = w;        w += (long)B * H * L * DK;
    float* kb = w;        w += (long)B * H * L * DK;
    float* vb = w;        w += (long)B * H * L * DK;
    float* attnout = w;   w += (long)B * L * DM;
    float* hp = w;        w += (long)B * L * DIM;

    // ---- GNN ----
    k_embed_fp<<<(B * N * DIM + 255) / 256, 256, 0, stream>>>(fingerprints, emb_fp, xs);
    for (int i = 0; i < LG; i++) {
        k_gnn_h<<<(B * N + 255) / 256, 256, 0, stream>>>(
            xs, fp_mask, Wg + i * DIM * DIM, bg + i * DIM, attn_a + i * 2 * DIM, h, s1, s2);
        k_gnn_att<<<B * (N / 16), 256, 0, stream>>>(h, s1, s2, adjacency, xs);
    }
    k_compound<<<B, 256, 0, stream>>>(xs, fp_mask, Watt, batt, compound, hc);

    // ---- Transformer ----
    k_pe<<<(L * DM + 255) / 256, 256, 0, stream>>>(pe);
    k_embed_word<<<(B * L * DM + 255) / 256, 256, 0, stream>>>(words, emb_word, pe, x);
    k_layernorm<<<B * L, DM, 0, stream>>>(x, ln1_g, ln1_b, xn);
    k_qkv<<<B * L / RF, 3 * DM, 0, stream>>>(xn, Wq, bq, Wk, bk, Wv, bv, qb, kb, vb);
    k_attn<<<B * H * (L / AQR), 256, 0, stream>>>(qb, kb, vb, words_mask, attnout);
    k_oproj<<<B * L / RF, DM, 0, stream>>>(attnout, Wo, bo, x);
    k_layernorm<<<B * L, DM, 0, stream>>>(x, ln2_g, ln2_b, xn);
    k_ffn<<<B * L / RF, DFF, 0, stream>>>(xn, W1, b1, W2, b2, x);
    k_lnf_hp<<<B * L, DM, 0, stream>>>(x, lnf_g, lnf_b, Wtout, btout, Watt, batt, hp);
    k_final<<<B, 256, 0, stream>>>(hp, hc, compound, Wout, bout, Wint, bint, out);
}